// Round 1
// baseline (281.680 us; speedup 1.0000x reference)
//
#include <hip/hip_runtime.h>
#include <hip/hip_bf16.h>
#include <stdint.h>

#define N_BATCH 16384
#define D_IN    2048
#define E_OUT   512
#define K_CONV  1537   // D_IN - E_OUT + 1
#define EPS_N   1e-12f

typedef unsigned short u16;
typedef __bf16 bf16x8 __attribute__((ext_vector_type(8)));
typedef float  f32x4  __attribute__((ext_vector_type(4)));

__device__ __forceinline__ u16 f2bf(float f) {
    union { float f; unsigned int u; } a; a.f = f;
    unsigned int r = a.u + 0x7FFFu + ((a.u >> 16) & 1u);   // RNE
    return (u16)(r >> 16);
}

// ---------------- x fp32 -> bf16 (8 elems/thread) ----------------
__global__ __launch_bounds__(256) void cvt_x_kernel(const float* __restrict__ x,
                                                    u16* __restrict__ xb) {
    int t = blockIdx.x * 256 + threadIdx.x;           // up to 4,194,304
    const float4* x4 = (const float4*)x;
    float4 a = x4[2 * t];
    float4 b = x4[2 * t + 1];
    uint4 o;
    o.x = (unsigned)f2bf(a.x) | ((unsigned)f2bf(a.y) << 16);
    o.y = (unsigned)f2bf(a.z) | ((unsigned)f2bf(a.w) << 16);
    o.z = (unsigned)f2bf(b.x) | ((unsigned)f2bf(b.y) << 16);
    o.w = (unsigned)f2bf(b.z) | ((unsigned)f2bf(b.w) << 16);
    ((uint4*)xb)[t] = o;
}

// ---------------- densify banded W into bf16 (E_OUT x D_IN) ----------------
__global__ __launch_bounds__(256) void prep_w_kernel(const float* __restrict__ w,
                                                     u16* __restrict__ wb) {
    int idx = blockIdx.x * 256 + threadIdx.x;          // E_OUT*D_IN threads
    int e = idx >> 11;                                 // D_IN = 2048 = 2^11
    int d = idx & (D_IN - 1);
    int k = d - e;
    float v = (k >= 0 && k < K_CONV) ? w[e * K_CONV + k] : 0.0f;
    wb[idx] = f2bf(v);
}

// ---------------- bf16 MFMA GEMM: C = A * B^T + bias ----------------
// A: (N_BATCH x D_IN) bf16 row-major; B: (E_OUT x D_IN) bf16 row-major
// band-aware K range per n-block.
__global__ __launch_bounds__(256, 2) void gemm_kernel(const u16* __restrict__ A,
                                                      const u16* __restrict__ B,
                                                      const float* __restrict__ bias,
                                                      float* __restrict__ C) {
    // k-plane LDS layout: [kb][row][8 bf16] ; element (row,kb) at byte off (kb*128+row)*16
    __shared__ __align__(16) u16 As[4][128][8];   // 8 KB
    __shared__ __align__(16) u16 Bs[4][128][8];   // 8 KB

    const int tid  = threadIdx.x;
    const int lane = tid & 63;
    const int wave = tid >> 6;
    const int quad = lane >> 4;
    const int r16  = lane & 15;
    const int wm   = (wave >> 1) << 6;   // 0 / 64
    const int wn   = (wave & 1) << 6;    // 0 / 64

    const int m0 = blockIdx.y * 128;
    const int n0 = blockIdx.x * 128;

    // band-limited K range: cols i in [n0, n0+128) need k in [n0, n0+128+K_CONV-1)
    const int k_begin = n0;                               // multiple of 32
    const int k_end   = min(D_IN, n0 + 128 + K_CONV - 1); // n0 + 1664 capped
    const int n_iters = (k_end - k_begin + 31) >> 5;      // == 52 for all blocks

    // staging: 512 16B-chunks per matrix, 256 threads -> 2 chunks each
    const int li0 = tid, li1 = tid + 256;
    const int ar0 = li0 & 127, ak0 = li0 >> 7;
    const int ar1 = li1 & 127, ak1 = li1 >> 7;

    const u16* ag0 = A + (size_t)(m0 + ar0) * D_IN + k_begin + ak0 * 8;
    const u16* ag1 = A + (size_t)(m0 + ar1) * D_IN + k_begin + ak1 * 8;
    const u16* bg0 = B + (size_t)(n0 + ar0) * D_IN + k_begin + ak0 * 8;
    const u16* bg1 = B + (size_t)(n0 + ar1) * D_IN + k_begin + ak1 * 8;

    u16* as0 = &As[0][0][0] + li0 * 8;
    u16* as1 = &As[0][0][0] + li1 * 8;
    u16* bs0 = &Bs[0][0][0] + li0 * 8;
    u16* bs1 = &Bs[0][0][0] + li1 * 8;

    f32x4 acc[4][4] = {};

    for (int it = 0; it < n_iters; ++it) {
        __builtin_amdgcn_global_load_lds((const __attribute__((address_space(1))) void*)ag0,
                                         (__attribute__((address_space(3))) void*)as0, 16, 0, 0);
        __builtin_amdgcn_global_load_lds((const __attribute__((address_space(1))) void*)ag1,
                                         (__attribute__((address_space(3))) void*)as1, 16, 0, 0);
        __builtin_amdgcn_global_load_lds((const __attribute__((address_space(1))) void*)bg0,
                                         (__attribute__((address_space(3))) void*)bs0, 16, 0, 0);
        __builtin_amdgcn_global_load_lds((const __attribute__((address_space(1))) void*)bg1,
                                         (__attribute__((address_space(3))) void*)bs1, 16, 0, 0);
        ag0 += 32; ag1 += 32; bg0 += 32; bg1 += 32;

        __syncthreads();   // compiler emits vmcnt(0) drain before s_barrier

        bf16x8 af[4], bf[4];
#pragma unroll
        for (int t = 0; t < 4; ++t)
            af[t] = *(const bf16x8*)&As[quad][wm + t * 16 + r16][0];
#pragma unroll
        for (int t = 0; t < 4; ++t)
            bf[t] = *(const bf16x8*)&Bs[quad][wn + t * 16 + r16][0];

#pragma unroll
        for (int i = 0; i < 4; ++i)
#pragma unroll
            for (int j = 0; j < 4; ++j)
                acc[i][j] = __builtin_amdgcn_mfma_f32_16x16x32_bf16(af[i], bf[j], acc[i][j], 0, 0, 0);

        __syncthreads();   // protect LDS from next iteration's staging
    }

    // epilogue: C rows = m (quad*4+reg), cols = n (lane&15); fuse bias
#pragma unroll
    for (int j = 0; j < 4; ++j) {
        const int col = n0 + wn + j * 16 + r16;
        const float bv = bias[col];
#pragma unroll
        for (int i = 0; i < 4; ++i) {
            const int rowb = m0 + wm + i * 16 + quad * 4;
#pragma unroll
            for (int rg = 0; rg < 4; ++rg)
                C[(size_t)(rowb + rg) * E_OUT + col] = acc[i][j][rg] + bv;
        }
    }
}

// ---------------- in-place row L2 normalize: 1 wave per 512-float row ----------------
__global__ __launch_bounds__(256) void norm_kernel(float* __restrict__ out) {
    const int wave = threadIdx.x >> 6;
    const int lane = threadIdx.x & 63;
    const size_t row = (size_t)blockIdx.x * 4 + wave;
    float4* p = (float4*)(out + row * E_OUT);
    float4 v0 = p[lane * 2];
    float4 v1 = p[lane * 2 + 1];
    float ss = v0.x * v0.x + v0.y * v0.y + v0.z * v0.z + v0.w * v0.w +
               v1.x * v1.x + v1.y * v1.y + v1.z * v1.z + v1.w * v1.w;
#pragma unroll
    for (int off = 32; off > 0; off >>= 1) ss += __shfl_xor(ss, off, 64);
    const float inv = 1.0f / fmaxf(sqrtf(ss), EPS_N);
    v0.x *= inv; v0.y *= inv; v0.z *= inv; v0.w *= inv;
    v1.x *= inv; v1.y *= inv; v1.z *= inv; v1.w *= inv;
    p[lane * 2] = v0;
    p[lane * 2 + 1] = v1;
}

// ---------------- fallback (only if ws too small): fused naive fp32 ----------------
__global__ __launch_bounds__(256) void naive_kernel(const float* __restrict__ x,
                                                    const float* __restrict__ w,
                                                    const float* __restrict__ b,
                                                    float* __restrict__ out) {
    __shared__ float xs[D_IN];
    __shared__ float os[E_OUT];
    __shared__ float red[4];
    const int n = blockIdx.x;
    const float* xr = x + (size_t)n * D_IN;
    for (int i = threadIdx.x; i < D_IN; i += 256) xs[i] = xr[i];
    __syncthreads();
    for (int i = threadIdx.x; i < E_OUT; i += 256) {
        float s = b[i];
        const float* wr = w + (size_t)i * K_CONV;
        for (int k = 0; k < K_CONV; ++k) s += wr[k] * xs[i + k];
        os[i] = s;
    }
    __syncthreads();
    float ss = 0.0f;
    for (int i = threadIdx.x; i < E_OUT; i += 256) ss += os[i] * os[i];
#pragma unroll
    for (int off = 32; off > 0; off >>= 1) ss += __shfl_xor(ss, off, 64);
    if ((threadIdx.x & 63) == 0) red[threadIdx.x >> 6] = ss;
    __syncthreads();
    const float inv = 1.0f / fmaxf(sqrtf(red[0] + red[1] + red[2] + red[3]), EPS_N);
    float* orow = out + (size_t)n * E_OUT;
    for (int i = threadIdx.x; i < E_OUT; i += 256) orow[i] = os[i] * inv;
}

extern "C" void kernel_launch(void* const* d_in, const int* in_sizes, int n_in,
                              void* d_out, int out_size, void* d_ws, size_t ws_size,
                              hipStream_t stream) {
    const float* x = (const float*)d_in[0];
    const float* w = (const float*)d_in[1];
    const float* b = (const float*)d_in[2];
    float* out = (float*)d_out;

    const size_t xb_bytes = (size_t)N_BATCH * D_IN * sizeof(u16);   // 64 MiB
    const size_t wb_bytes = (size_t)E_OUT * D_IN * sizeof(u16);     //  2 MiB

    if (ws_size < xb_bytes + wb_bytes) {
        naive_kernel<<<N_BATCH, 256, 0, stream>>>(x, w, b, out);
        return;
    }

    u16* xb = (u16*)d_ws;
    u16* wb = (u16*)((char*)d_ws + xb_bytes);

    cvt_x_kernel<<<(N_BATCH * D_IN / 8) / 256, 256, 0, stream>>>(x, xb);
    prep_w_kernel<<<(E_OUT * D_IN) / 256, 256, 0, stream>>>(w, wb);

    dim3 grid(E_OUT / 128, N_BATCH / 128);   // (4, 128): n fastest for A-tile L2 sharing
    gemm_kernel<<<grid, 256, 0, stream>>>(xb, wb, b, out);

    norm_kernel<<<N_BATCH / 4, 256, 0, stream>>>(out);
}